// Round 1
// baseline (222.258 us; speedup 1.0000x reference)
//
#include <hip/hip_runtime.h>

// Problem constants (match reference setup_inputs)
#define B    64
#define OBJS 2048
#define NTOT (B * OBJS)       // 131072
#define D    256
#define K    2
#define S1   16               // blocks per scene for heavy passes
#define CH   (OBJS / S1)      // 128 rows per block
#define RPW  (CH / 4)         // 32 rows per wave (contiguous chunk)

// Workspace layout (floats); ws is far larger than needed.
#define WS_P1  0                          // 1024 * 256  phase-1 partial ctx sums
#define WS_UP  (1024 * 256)               // 1024 * 512  phase-2 partial U
#define WS_ZP  (WS_UP + 1024 * 512)       // 1024 * 8    phase-2 partial Z
#define WS_E   (WS_ZP + 1024 * 8)         // NTOT * 2    exp(logit) per row (16B aligned)
#define WS_CNT (WS_E + NTOT * 2)          // 2*B ints: arrival + finalize counters

static __device__ __forceinline__ float lrelu02(float v) {
    return v > 0.0f ? v : 0.2f * v;
}

// ============================================================================
// Fused single-dispatch kernel (cooperative launch): per-scene sync replaces
// the two kernel-boundary global drains; last block per scene finalizes.
// __launch_bounds__(256,4): cap VGPR at 128 -> 4 blocks/CU -> 1024 co-resident.
// ============================================================================
__global__ __launch_bounds__(256, 4) void fused_all(
        const float* __restrict__ x,
        const int* __restrict__ num_objs,
        const float* __restrict__ att_scale,
        const float* __restrict__ att_shared,
        const float* __restrict__ channel_bias,
        float* __restrict__ ws,
        float* __restrict__ out) {
    __shared__ float pl[4 * 576];       // phase1 reduce buf / phase2 transpose buf
    __shared__ float esm[4 * 16];
    __shared__ float sctx[D];
    __shared__ float sbt[2];
    __shared__ int   sfin;

    int blk = blockIdx.x;
    int b = blk >> 4;
    int t = threadIdx.x;
    int w = t >> 6, l = t & 63;
    int r = l & 7, sl = l >> 3;
    int row0 = blk * CH + w * RPW;      // contiguous 32-row chunk per wave
    int* cntA = (int*)(ws + WS_CNT);    // [B] phase-1 arrival counters
    int* cntF = cntA + B;               // [B] finalize counters

    // ---------------- phase 1: per-block partial ctx column sums ----------------
    {
        float4 acc = make_float4(0.f, 0.f, 0.f, 0.f);
        const float* px = x + (size_t)row0 * D + 4 * l;
#pragma unroll 8
        for (int j = 0; j < RPW; ++j) {
            float4 v = *(const float4*)(px + (size_t)j * D);
            acc.x += v.x; acc.y += v.y; acc.z += v.z; acc.w += v.w;
        }
        *(float4*)(pl + w * D + 4 * l) = acc;
        __syncthreads();
        if (t < 64) {
            float4 a = ((const float4*)(pl        ))[t];
            float4 e = ((const float4*)(pl +     D))[t];
            float4 f = ((const float4*)(pl + 2 * D))[t];
            float4 g = ((const float4*)(pl + 3 * D))[t];
            float4 s4 = make_float4(a.x + e.x + f.x + g.x, a.y + e.y + f.y + g.y,
                                    a.z + e.z + f.z + g.z, a.w + e.w + f.w + g.w);
            *(float4*)(ws + WS_P1 + blk * D + 4 * t) = s4;
        }
        __syncthreads();
        // publish + wait for this scene's 16 blocks (per-scene, ragged across scenes)
        if (t == 0) {
            __threadfence();                       // release our partial sums
            atomicAdd(&cntA[b], 1);                // device-scope (m20)
            while (__hip_atomic_load(&cntA[b], __ATOMIC_RELAXED,
                                     __HIP_MEMORY_SCOPE_AGENT) < S1)
                __builtin_amdgcn_s_sleep(2);       // relaxed poll: no cache inv storm
            __threadfence();                       // acquire peers' partials
        }
        __syncthreads();
    }

    // ---------------- phase 2: main pass (k2 body) ----------------
    // prologue A: reduce this scene's 16 ctx partials (16 KB, L2/L3-hit)
    {
        int cnt = num_objs[b]; if (cnt < 1) cnt = 1;
        float inv = 1.0f / (float)cnt;
        float sum = 0.f;
#pragma unroll
        for (int c = 0; c < S1; ++c) sum += ws[WS_P1 + (b * S1 + c) * D + t];
        sctx[t] = sum * inv;
    }
    // prologue B: bias_term[k] = channel_bias[k,:] . att_shared (wave 0)
    if (t < 64) {
        float4 a = ((const float4*)att_shared)[t];
#pragma unroll
        for (int k = 0; k < K; ++k) {
            float4 cb = ((const float4*)(channel_bias + k * D))[t];
            float v = a.x * cb.x + a.y * cb.y + a.z * cb.z + a.w * cb.w;
#pragma unroll
            for (int m = 32; m > 0; m >>= 1) v += __shfl_xor(v, m);
            if (t == 0) sbt[k] = v;
        }
    }
    __syncthreads();

    float4 a4   = ((const float4*)att_shared)[l];
    float4 ctx4 = *(const float4*)(sctx + 4 * l);
    float bt0 = sbt[0], bt1 = sbt[1];
    float s0 = att_scale[0], s1 = att_scale[1];

    float4 acc0 = make_float4(0.f, 0.f, 0.f, 0.f);
    float4 acc1 = make_float4(0.f, 0.f, 0.f, 0.f);
    float z0 = 0.f, z1 = 0.f;
    float e0c = 0.f, e1c = 0.f;            // lane l<32 captures row (row0 + l)'s exps
    float* pw = pl  + w * 576;
    float* ew = esm + w * 16;
    const float* px = x + (size_t)row0 * D + 4 * l;

#pragma unroll
    for (int g = 0; g < 4; ++g) {
        float4 v0 = *(const float4*)(px + (size_t)(g * 8 + 0) * D);
        float4 v1 = *(const float4*)(px + (size_t)(g * 8 + 1) * D);
        float4 v2 = *(const float4*)(px + (size_t)(g * 8 + 2) * D);
        float4 v3 = *(const float4*)(px + (size_t)(g * 8 + 3) * D);
        float4 v4 = *(const float4*)(px + (size_t)(g * 8 + 4) * D);
        float4 v5 = *(const float4*)(px + (size_t)(g * 8 + 5) * D);
        float4 v6 = *(const float4*)(px + (size_t)(g * 8 + 6) * D);
        float4 v7 = *(const float4*)(px + (size_t)(g * 8 + 7) * D);

#define PDOT(V) (lrelu02((V).x + ctx4.x) * a4.x + lrelu02((V).y + ctx4.y) * a4.y \
               + lrelu02((V).z + ctx4.z) * a4.z + lrelu02((V).w + ctx4.w) * a4.w)
        // per-lane partial dots -> LDS (stride-9: conflict-free)
        pw[l * 9 + 0] = PDOT(v0); pw[l * 9 + 1] = PDOT(v1);
        pw[l * 9 + 2] = PDOT(v2); pw[l * 9 + 3] = PDOT(v3);
        pw[l * 9 + 4] = PDOT(v4); pw[l * 9 + 5] = PDOT(v5);
        pw[l * 9 + 6] = PDOT(v6); pw[l * 9 + 7] = PDOT(v7);
#undef PDOT
        // lane (r,sl) sums orig-lanes 8sl..8sl+7 for row r (2-way bank alias: free)
        float tr = 0.f;
#pragma unroll
        for (int q = 0; q < 8; ++q) tr += pw[(sl * 8 + q) * 9 + r];
        tr += __shfl_xor(tr, 8);
        tr += __shfl_xor(tr, 16);
        tr += __shfl_xor(tr, 32);      // all lanes now hold base of row g*8 + (l&7)

        float e0 = __expf((tr + bt0) * s0);
        float e1 = __expf((tr + bt1) * s1);
        // lane l (l<32) owns row row0+l = row0 + ((l>>3)&3)*8 + (l&7)
        if (((l >> 3) & 3) == g) { e0c = e0; e1c = e1; }
        if (l < 8) { ew[2 * l] = e0; ew[2 * l + 1] = e1; }
        float4 E0 = *(const float4*)(ew + 0);   // (e0[0],e1[0],e0[1],e1[1])
        float4 E1 = *(const float4*)(ew + 4);
        float4 E2 = *(const float4*)(ew + 8);
        float4 E3 = *(const float4*)(ew + 12);
        z0 += E0.x + E0.z + E1.x + E1.z + E2.x + E2.z + E3.x + E3.z;
        z1 += E0.y + E0.w + E1.y + E1.w + E2.y + E2.w + E3.y + E3.w;

#define ACC(V, EA, EB) { acc0.x += (V).x * (EA); acc0.y += (V).y * (EA);      \
                         acc0.z += (V).z * (EA); acc0.w += (V).w * (EA);      \
                         acc1.x += (V).x * (EB); acc1.y += (V).y * (EB);      \
                         acc1.z += (V).z * (EB); acc1.w += (V).w * (EB); }
        ACC(v0, E0.x, E0.y) ACC(v1, E0.z, E0.w)
        ACC(v2, E1.x, E1.y) ACC(v3, E1.z, E1.w)
        ACC(v4, E2.x, E2.y) ACC(v5, E2.z, E2.w)
        ACC(v6, E3.x, E3.y) ACC(v7, E3.z, E3.w)
#undef ACC
    }

    // e store: lane l (l<32) owns row row0 + l (coalesced float2) — lanes 32..63
    // hold duplicates of rows owned by the NEXT wave's chunk and must NOT store.
    if (l < 32) ((float2*)(ws + WS_E))[row0 + l] = make_float2(e0c, e1c);
    // per-wave Z partial
    if (l == 0) {
        ws[WS_ZP + blk * 8 + w * 2 + 0] = z0;
        ws[WS_ZP + blk * 8 + w * 2 + 1] = z1;
    }
    // cross-wave U reduce in LDS (reuse pl), one coalesced 2 KB store per block
    __syncthreads();
    {
        int base = w * (D * K) + l * 8;   // col (4l+m)*2+k within wave region
        pl[base + 0] = acc0.x; pl[base + 1] = acc1.x;
        pl[base + 2] = acc0.y; pl[base + 3] = acc1.y;
        pl[base + 4] = acc0.z; pl[base + 5] = acc1.z;
        pl[base + 6] = acc0.w; pl[base + 7] = acc1.w;
    }
    __syncthreads();
    if (t < 128) {
        float4 a = ((const float4*)(pl       ))[t];
        float4 e = ((const float4*)(pl +  512))[t];
        float4 f = ((const float4*)(pl + 1024))[t];
        float4 g = ((const float4*)(pl + 1536))[t];
        float4 s4 = make_float4(a.x + e.x + f.x + g.x, a.y + e.y + f.y + g.y,
                                a.z + e.z + f.z + g.z, a.w + e.w + f.w + g.w);
        *(float4*)(ws + WS_UP + (size_t)blk * (D * K) + 4 * t) = s4;
    }

    // ---------------- phase 3: last block of each scene finalizes ----------------
    __syncthreads();
    if (t == 0) {
        __threadfence();                       // release U/Z/E partials
        int old = atomicAdd(&cntF[b], 1);
        sfin = (old == S1 - 1) ? 1 : 0;
        if (sfin) __threadfence();             // acquire peers' partials
    }
    __syncthreads();
    if (!sfin) return;

    // k3 body: waves 0/1 reduce Z for channel 0/1 (64 partials each)
    if (w < 2) {
        float v = ws[WS_ZP + (b * S1 + (l >> 2)) * 8 + (l & 3) * 2 + w];
#pragma unroll
        for (int m = 32; m > 0; m >>= 1) v += __shfl_xor(v, m);
        if (l == 0) sbt[w] = v;
    }
    __syncthreads();
    float zf0 = sbt[0], zf1 = sbt[1];
    float iz0 = 1.0f / zf0, iz1 = 1.0f / zf1;

    // features: out[b*512 + j], j = d*2+k
#pragma unroll
    for (int j = t; j < D * K; j += 256) {
        float ssum = 0.f;
#pragma unroll
        for (int c = 0; c < S1; ++c) ssum += ws[WS_UP + (b * S1 + c) * (D * K) + j];
        out[b * (D * K) + j] = ssum * ((j & 1) ? iz1 : iz0);
    }
    // weights: float4 = 2 rows at a time
    const float4* E = (const float4*)(ws + WS_E);
    float4* W = (float4*)(out + B * D * K);
#pragma unroll
    for (int i = t; i < OBJS / 2; i += 256) {
        float4 e4 = E[b * (OBJS / 2) + i];
        W[b * (OBJS / 2) + i] = make_float4(e4.x * iz0, e4.y * iz1, e4.z * iz0, e4.w * iz1);
    }
}

// ============================================================================
// Fallback path: the previous verified 3-kernel pipeline (used only if the
// cooperative launch cannot guarantee 1024 co-resident blocks).
// ============================================================================
__global__ __launch_bounds__(256) void k1_partial(const float* __restrict__ x,
                                                  float* __restrict__ ws) {
    __shared__ float red[4 * D];
    int blk = blockIdx.x;
    int w = threadIdx.x >> 6, l = threadIdx.x & 63;
    int row0 = blk * CH + w * RPW;

    float4 acc = make_float4(0.f, 0.f, 0.f, 0.f);
    const float* px = x + (size_t)row0 * D + 4 * l;
#pragma unroll 8
    for (int j = 0; j < RPW; ++j) {
        float4 v = *(const float4*)(px + (size_t)j * D);
        acc.x += v.x; acc.y += v.y; acc.z += v.z; acc.w += v.w;
    }
    *(float4*)(red + w * D + 4 * l) = acc;
    __syncthreads();
    int t = threadIdx.x;
    if (t < 64) {
        float4 a = ((const float4*)(red        ))[t];
        float4 e = ((const float4*)(red +     D))[t];
        float4 f = ((const float4*)(red + 2 * D))[t];
        float4 g = ((const float4*)(red + 3 * D))[t];
        float4 s = make_float4(a.x + e.x + f.x + g.x, a.y + e.y + f.y + g.y,
                               a.z + e.z + f.z + g.z, a.w + e.w + f.w + g.w);
        *(float4*)(ws + WS_P1 + blk * D + 4 * t) = s;
    }
}

__global__ __launch_bounds__(256) void k2_main(const float* __restrict__ x,
                                               const int* __restrict__ num_objs,
                                               const float* __restrict__ att_scale,
                                               const float* __restrict__ att_shared,
                                               const float* __restrict__ channel_bias,
                                               float* __restrict__ ws) {
    __shared__ float pl[4 * 576];
    __shared__ float esm[4 * 16];
    __shared__ float sctx[D];
    __shared__ float sbt[2];

    int blk = blockIdx.x;
    int b = blk >> 4;
    int t = threadIdx.x;
    int w = t >> 6, l = t & 63;
    int r = l & 7, s = l >> 3;
    int row0 = blk * CH + w * RPW;

    {
        int cnt = num_objs[b]; if (cnt < 1) cnt = 1;
        float inv = 1.0f / (float)cnt;
        float sum = 0.f;
#pragma unroll
        for (int c = 0; c < S1; ++c) sum += ws[WS_P1 + (b * S1 + c) * D + t];
        sctx[t] = sum * inv;
    }
    if (t < 64) {
        float4 a = ((const float4*)att_shared)[t];
#pragma unroll
        for (int k = 0; k < K; ++k) {
            float4 cb = ((const float4*)(channel_bias + k * D))[t];
            float v = a.x * cb.x + a.y * cb.y + a.z * cb.z + a.w * cb.w;
#pragma unroll
            for (int m = 32; m > 0; m >>= 1) v += __shfl_xor(v, m);
            if (t == 0) sbt[k] = v;
        }
    }
    __syncthreads();

    float4 a4   = ((const float4*)att_shared)[l];
    float4 ctx4 = *(const float4*)(sctx + 4 * l);
    float bt0 = sbt[0], bt1 = sbt[1];
    float s0 = att_scale[0], s1 = att_scale[1];

    float4 acc0 = make_float4(0.f, 0.f, 0.f, 0.f);
    float4 acc1 = make_float4(0.f, 0.f, 0.f, 0.f);
    float z0 = 0.f, z1 = 0.f;
    float e0c = 0.f, e1c = 0.f;
    float* pw = pl  + w * 576;
    float* ew = esm + w * 16;
    const float* px = x + (size_t)row0 * D + 4 * l;

#pragma unroll
    for (int g = 0; g < 4; ++g) {
        float4 v0 = *(const float4*)(px + (size_t)(g * 8 + 0) * D);
        float4 v1 = *(const float4*)(px + (size_t)(g * 8 + 1) * D);
        float4 v2 = *(const float4*)(px + (size_t)(g * 8 + 2) * D);
        float4 v3 = *(const float4*)(px + (size_t)(g * 8 + 3) * D);
        float4 v4 = *(const float4*)(px + (size_t)(g * 8 + 4) * D);
        float4 v5 = *(const float4*)(px + (size_t)(g * 8 + 5) * D);
        float4 v6 = *(const float4*)(px + (size_t)(g * 8 + 6) * D);
        float4 v7 = *(const float4*)(px + (size_t)(g * 8 + 7) * D);

#define PDOT(V) (lrelu02((V).x + ctx4.x) * a4.x + lrelu02((V).y + ctx4.y) * a4.y \
               + lrelu02((V).z + ctx4.z) * a4.z + lrelu02((V).w + ctx4.w) * a4.w)
        pw[l * 9 + 0] = PDOT(v0); pw[l * 9 + 1] = PDOT(v1);
        pw[l * 9 + 2] = PDOT(v2); pw[l * 9 + 3] = PDOT(v3);
        pw[l * 9 + 4] = PDOT(v4); pw[l * 9 + 5] = PDOT(v5);
        pw[l * 9 + 6] = PDOT(v6); pw[l * 9 + 7] = PDOT(v7);
#undef PDOT
        float tr = 0.f;
#pragma unroll
        for (int q = 0; q < 8; ++q) tr += pw[(s * 8 + q) * 9 + r];
        tr += __shfl_xor(tr, 8);
        tr += __shfl_xor(tr, 16);
        tr += __shfl_xor(tr, 32);

        float e0 = __expf((tr + bt0) * s0);
        float e1 = __expf((tr + bt1) * s1);
        if (((l >> 3) & 3) == g) { e0c = e0; e1c = e1; }
        if (l < 8) { ew[2 * l] = e0; ew[2 * l + 1] = e1; }
        float4 E0 = *(const float4*)(ew + 0);
        float4 E1 = *(const float4*)(ew + 4);
        float4 E2 = *(const float4*)(ew + 8);
        float4 E3 = *(const float4*)(ew + 12);
        z0 += E0.x + E0.z + E1.x + E1.z + E2.x + E2.z + E3.x + E3.z;
        z1 += E0.y + E0.w + E1.y + E1.w + E2.y + E2.w + E3.y + E3.w;

#define ACC(V, EA, EB) { acc0.x += (V).x * (EA); acc0.y += (V).y * (EA);      \
                         acc0.z += (V).z * (EA); acc0.w += (V).w * (EA);      \
                         acc1.x += (V).x * (EB); acc1.y += (V).y * (EB);      \
                         acc1.z += (V).z * (EB); acc1.w += (V).w * (EB); }
        ACC(v0, E0.x, E0.y) ACC(v1, E0.z, E0.w)
        ACC(v2, E1.x, E1.y) ACC(v3, E1.z, E1.w)
        ACC(v4, E2.x, E2.y) ACC(v5, E2.z, E2.w)
        ACC(v6, E3.x, E3.y) ACC(v7, E3.z, E3.w)
#undef ACC
    }

    if (l < 32) ((float2*)(ws + WS_E))[row0 + l] = make_float2(e0c, e1c);
    if (l == 0) {
        ws[WS_ZP + blk * 8 + w * 2 + 0] = z0;
        ws[WS_ZP + blk * 8 + w * 2 + 1] = z1;
    }
    __syncthreads();
    {
        int base = w * (D * K) + l * 8;
        pl[base + 0] = acc0.x; pl[base + 1] = acc1.x;
        pl[base + 2] = acc0.y; pl[base + 3] = acc1.y;
        pl[base + 4] = acc0.z; pl[base + 5] = acc1.z;
        pl[base + 6] = acc0.w; pl[base + 7] = acc1.w;
    }
    __syncthreads();
    if (t < 128) {
        float4 a = ((const float4*)(pl       ))[t];
        float4 e = ((const float4*)(pl +  512))[t];
        float4 f = ((const float4*)(pl + 1024))[t];
        float4 g = ((const float4*)(pl + 1536))[t];
        float4 s4 = make_float4(a.x + e.x + f.x + g.x, a.y + e.y + f.y + g.y,
                                a.z + e.z + f.z + g.z, a.w + e.w + f.w + g.w);
        *(float4*)(ws + WS_UP + (size_t)blk * (D * K) + 4 * t) = s4;
    }
}

__global__ __launch_bounds__(256) void k3_final(const float* __restrict__ ws,
                                                float* __restrict__ out) {
    __shared__ float zsh[2];
    int b = blockIdx.x;
    int t = threadIdx.x;
    int w = t >> 6, l = t & 63;

    if (w < 2) {
        float v = ws[WS_ZP + (b * S1 + (l >> 2)) * 8 + (l & 3) * 2 + w];
#pragma unroll
        for (int m = 32; m > 0; m >>= 1) v += __shfl_xor(v, m);
        if (l == 0) zsh[w] = v;
    }
    __syncthreads();
    float z0 = zsh[0], z1 = zsh[1];
    float iz0 = 1.0f / z0, iz1 = 1.0f / z1;

#pragma unroll
    for (int j = t; j < D * K; j += 256) {
        float s = 0.f;
#pragma unroll
        for (int c = 0; c < S1; ++c) s += ws[WS_UP + (b * S1 + c) * (D * K) + j];
        out[b * (D * K) + j] = s * ((j & 1) ? iz1 : iz0);
    }
    const float4* E = (const float4*)(ws + WS_E);
    float4* W = (float4*)(out + B * D * K);
#pragma unroll
    for (int i = t; i < OBJS / 2; i += 256) {
        float4 e = E[b * (OBJS / 2) + i];
        W[b * (OBJS / 2) + i] = make_float4(e.x * iz0, e.y * iz1, e.z * iz0, e.w * iz1);
    }
}

extern "C" void kernel_launch(void* const* d_in, const int* in_sizes, int n_in,
                              void* d_out, int out_size, void* d_ws, size_t ws_size,
                              hipStream_t stream) {
    const float* x            = (const float*)d_in[0];   // [N, D]
    const int*   num_objs     = (const int*)d_in[1];     // [B]
    const float* att_shared   = (const float*)d_in[2];   // [1, D]
    const float* att_scale    = (const float*)d_in[3];   // [K, 1]
    const float* channel_bias = (const float*)d_in[4];   // [K, D]
    float* ws  = (float*)d_ws;
    float* out = (float*)d_out;

    // One-time check: can the fused kernel keep all 1024 blocks co-resident?
    static int coop_ok = -1;
    if (coop_ok < 0) {
        int nb = 0;
        hipError_t e = hipOccupancyMaxActiveBlocksPerMultiprocessor(
                &nb, fused_all, 256, 0);
        coop_ok = (e == hipSuccess && nb >= 4) ? 1 : 0;
    }

    if (coop_ok) {
        // ws is re-poisoned each iteration: counters MUST be zeroed in-graph.
        hipMemsetAsync((char*)d_ws + sizeof(float) * (size_t)WS_CNT, 0,
                       2 * B * sizeof(int), stream);
        void* args[] = {(void*)&x, (void*)&num_objs, (void*)&att_scale,
                        (void*)&att_shared, (void*)&channel_bias,
                        (void*)&ws, (void*)&out};
        hipError_t e = hipLaunchCooperativeKernel((void*)fused_all,
                                                  dim3(B * S1), dim3(256),
                                                  args, 0, stream);
        if (e == hipSuccess) return;
        coop_ok = 0;  // fall through to the proven 3-kernel path
    }

    k1_partial<<<B * S1, 256, 0, stream>>>(x, ws);
    k2_main<<<B * S1, 256, 0, stream>>>(x, num_objs, att_scale, att_shared,
                                        channel_bias, ws);
    k3_final<<<B, 256, 0, stream>>>(ws, out);
}

// Round 2
// 221.095 us; speedup vs baseline: 1.0053x; 1.0053x over previous
//
#include <hip/hip_runtime.h>

// Problem constants (match reference setup_inputs)
#define B    64
#define OBJS 2048
#define NTOT (B * OBJS)       // 131072
#define D    256
#define K    2

// ---- fused single-pass geometry: 256 blocks, 1 block/CU, 4 blocks/scene ----
#define NBLK 256
#define BPS  4                // blocks per scene
#define CHF  (OBJS / BPS)     // 512 rows per block
#define RPWF (CHF / 4)        // 128 rows per wave
// per-wave row layout: groups of 8 rows; 16 groups total
//   groups 0..9   -> registers (kp[10][8] = 320 VGPR)
//   groups 10..13 -> LDS (32 rows * 1KB = 32KB/wave, 128KB/block dynamic)
//   groups 14..15 -> re-streamed in phase 2 (16 rows, ~17MB total, L3-hot)

// ---- fallback 3-kernel geometry ----
#define S1   16               // blocks per scene for fallback heavy passes
#define CH   (OBJS / S1)      // 128 rows per block
#define RPW  (CH / 4)         // 32 rows per wave

// Workspace layout (floats); ws is far larger than needed.
#define WS_P1  0                          // partial ctx sums (per block)
#define WS_UP  (1024 * 256)               // partial U (per block)
#define WS_ZP  (WS_UP + 1024 * 512)       // partial Z (per block)
#define WS_E   (WS_ZP + 1024 * 8)         // NTOT * 2 exp(logit) per row (16B aligned)
#define WS_CNT (WS_E + NTOT * 2)          // 2*B ints: arrival + finalize counters

static __device__ __forceinline__ float lrelu02(float v) {
    return v > 0.0f ? v : 0.2f * v;
}

// ============================================================================
// Fused single-PASS kernel: x is read from HBM exactly once. Each block
// retains its 512-row chunk across the per-scene barrier in regs+LDS.
// __launch_bounds__(256,1): 1 wave/SIMD -> up to 512 VGPR/wave.
// ============================================================================
__global__ __launch_bounds__(256, 1) void fused_all(
        const float* __restrict__ x,
        const int* __restrict__ num_objs,
        const float* __restrict__ att_scale,
        const float* __restrict__ att_shared,
        const float* __restrict__ channel_bias,
        float* __restrict__ ws,
        float* __restrict__ out) {
    extern __shared__ float4 xbuf4[];   // [4 waves][32 rows][64 lanes] = 128 KB
    __shared__ float pl[4 * 576];       // phase1 reduce buf / phase2 transpose buf
    __shared__ float esm[4 * 16];
    __shared__ float sctx[D];
    __shared__ float sbt[2];
    __shared__ int   sfin;

    int blk = blockIdx.x;
    int b = blk / BPS;
    int t = threadIdx.x;
    int w = t >> 6, l = t & 63;
    int r = l & 7, sl = l >> 3;
    int row0 = blk * CHF + w * RPWF;    // contiguous 128-row chunk per wave
    int* cntA = (int*)(ws + WS_CNT);    // [B] phase-1 arrival counters
    int* cntF = cntA + B;               // [B] finalize counters

    float4 kp[10][8];                   // retained rows 0..79 (constant-indexed)
    float4* xw = xbuf4 + (size_t)w * (32 * 64);
    const float* px = x + (size_t)row0 * D + 4 * l;

    // ---------------- phase 1: single read of x; retain + column-sum ----------------
    float4 acc = make_float4(0.f, 0.f, 0.f, 0.f);
#pragma unroll
    for (int g = 0; g < 10; ++g) {
#pragma unroll
        for (int j = 0; j < 8; ++j) {
            float4 v = *(const float4*)(px + (size_t)(g * 8 + j) * D);
            kp[g][j] = v;
            acc.x += v.x; acc.y += v.y; acc.z += v.z; acc.w += v.w;
        }
    }
#pragma unroll
    for (int gl = 0; gl < 32; ++gl) {   // rows 80..111 -> LDS
        float4 v = *(const float4*)(px + (size_t)(80 + gl) * D);
        xw[gl * 64 + l] = v;
        acc.x += v.x; acc.y += v.y; acc.z += v.z; acc.w += v.w;
    }
#pragma unroll
    for (int j = 0; j < 16; ++j) {      // rows 112..127 -> sum only (re-streamed later)
        float4 v = *(const float4*)(px + (size_t)(112 + j) * D);
        acc.x += v.x; acc.y += v.y; acc.z += v.z; acc.w += v.w;
    }
    // cross-wave reduce of column sums -> WS_P1
    *(float4*)(pl + w * D + 4 * l) = acc;
    __syncthreads();
    if (t < 64) {
        float4 a = ((const float4*)(pl        ))[t];
        float4 e = ((const float4*)(pl +     D))[t];
        float4 f = ((const float4*)(pl + 2 * D))[t];
        float4 g = ((const float4*)(pl + 3 * D))[t];
        float4 s4 = make_float4(a.x + e.x + f.x + g.x, a.y + e.y + f.y + g.y,
                                a.z + e.z + f.z + g.z, a.w + e.w + f.w + g.w);
        *(float4*)(ws + WS_P1 + blk * D + 4 * t) = s4;
    }
    __syncthreads();
    // publish + wait for this scene's 4 blocks (per-scene, ragged across scenes)
    if (t == 0) {
        __threadfence();                       // release our partial sums
        atomicAdd(&cntA[b], 1);                // device-scope (m20)
        while (__hip_atomic_load(&cntA[b], __ATOMIC_RELAXED,
                                 __HIP_MEMORY_SCOPE_AGENT) < BPS)
            __builtin_amdgcn_s_sleep(2);       // relaxed poll
        __threadfence();                       // acquire peers' partials
    }
    __syncthreads();

    // ---------------- phase 2: compute entirely from retained data ----------------
    // prologue A: reduce this scene's 4 ctx partials (L2-hot)
    {
        int cnt = num_objs[b]; if (cnt < 1) cnt = 1;
        float inv = 1.0f / (float)cnt;
        float sum = 0.f;
#pragma unroll
        for (int c = 0; c < BPS; ++c) sum += ws[WS_P1 + (b * BPS + c) * D + t];
        sctx[t] = sum * inv;
    }
    // prologue B: bias_term[k] = channel_bias[k,:] . att_shared (wave 0)
    if (t < 64) {
        float4 a = ((const float4*)att_shared)[t];
#pragma unroll
        for (int k = 0; k < K; ++k) {
            float4 cb = ((const float4*)(channel_bias + k * D))[t];
            float v = a.x * cb.x + a.y * cb.y + a.z * cb.z + a.w * cb.w;
#pragma unroll
            for (int m = 32; m > 0; m >>= 1) v += __shfl_xor(v, m);
            if (t == 0) sbt[k] = v;
        }
    }
    __syncthreads();

    float4 a4   = ((const float4*)att_shared)[l];
    float4 ctx4 = *(const float4*)(sctx + 4 * l);
    float bt0 = sbt[0], bt1 = sbt[1];
    float s0 = att_scale[0], s1 = att_scale[1];

    float4 acc0 = make_float4(0.f, 0.f, 0.f, 0.f);
    float4 acc1 = make_float4(0.f, 0.f, 0.f, 0.f);
    float z0 = 0.f, z1 = 0.f;
    float e0c = 0.f, e1c = 0.f;    // lane l owns row row0 + l       (groups 0..7)
    float e0d = 0.f, e1d = 0.f;    // lane l owns row row0 + 64 + l  (groups 8..15)
    float* pw = pl  + w * 576;
    float* ew = esm + w * 16;

#define PD(V) (lrelu02((V).x + ctx4.x) * a4.x + lrelu02((V).y + ctx4.y) * a4.y \
             + lrelu02((V).z + ctx4.z) * a4.z + lrelu02((V).w + ctx4.w) * a4.w)
#define ACC(V, EA, EB) { acc0.x += (V).x * (EA); acc0.y += (V).y * (EA);      \
                         acc0.z += (V).z * (EA); acc0.w += (V).w * (EA);      \
                         acc1.x += (V).x * (EB); acc1.y += (V).y * (EB);      \
                         acc1.z += (V).z * (EB); acc1.w += (V).w * (EB); }
#define PROC_GROUP(GI, L0, L1, L2, L3, L4, L5, L6, L7) {                      \
    pw[l * 9 + 0] = PD(L0); pw[l * 9 + 1] = PD(L1);                           \
    pw[l * 9 + 2] = PD(L2); pw[l * 9 + 3] = PD(L3);                           \
    pw[l * 9 + 4] = PD(L4); pw[l * 9 + 5] = PD(L5);                           \
    pw[l * 9 + 6] = PD(L6); pw[l * 9 + 7] = PD(L7);                           \
    float tr = 0.f;                                                           \
    _Pragma("unroll")                                                         \
    for (int q = 0; q < 8; ++q) tr += pw[(sl * 8 + q) * 9 + r];               \
    tr += __shfl_xor(tr, 8);                                                  \
    tr += __shfl_xor(tr, 16);                                                 \
    tr += __shfl_xor(tr, 32);                                                 \
    float e0 = __expf((tr + bt0) * s0);                                       \
    float e1 = __expf((tr + bt1) * s1);                                       \
    if ((GI) == (l >> 3))     { e0c = e0; e1c = e1; }                         \
    if ((GI) == 8 + (l >> 3)) { e0d = e0; e1d = e1; }                         \
    if (l < 8) { ew[2 * l] = e0; ew[2 * l + 1] = e1; }                        \
    float4 E0 = *(const float4*)(ew + 0);                                     \
    float4 E1 = *(const float4*)(ew + 4);                                     \
    float4 E2 = *(const float4*)(ew + 8);                                     \
    float4 E3 = *(const float4*)(ew + 12);                                    \
    z0 += E0.x + E0.z + E1.x + E1.z + E2.x + E2.z + E3.x + E3.z;              \
    z1 += E0.y + E0.w + E1.y + E1.w + E2.y + E2.w + E3.y + E3.w;              \
    ACC(L0, E0.x, E0.y) ACC(L1, E0.z, E0.w)                                   \
    ACC(L2, E1.x, E1.y) ACC(L3, E1.z, E1.w)                                   \
    ACC(L4, E2.x, E2.y) ACC(L5, E2.z, E2.w)                                   \
    ACC(L6, E3.x, E3.y) ACC(L7, E3.z, E3.w)                                   \
}
#define PG_KP(G) PROC_GROUP(G, kp[G][0], kp[G][1], kp[G][2], kp[G][3],        \
                               kp[G][4], kp[G][5], kp[G][6], kp[G][7])

    PG_KP(0) PG_KP(1) PG_KP(2) PG_KP(3)
    // issue the re-stream loads for rows 112..127 now (still L3/L2-hot; the
    // next 10 group bodies cover the HBM/L3 latency)
    float4 sa[8], sb[8];
#pragma unroll
    for (int j = 0; j < 8; ++j) sa[j] = *(const float4*)(px + (size_t)(112 + j) * D);
#pragma unroll
    for (int j = 0; j < 8; ++j) sb[j] = *(const float4*)(px + (size_t)(120 + j) * D);

    PG_KP(4) PG_KP(5) PG_KP(6) PG_KP(7) PG_KP(8) PG_KP(9)
    // LDS-retained groups 10..13 (rows 80..111)
    {
        float4 q0 = xw[0 * 64 + l], q1 = xw[1 * 64 + l], q2 = xw[2 * 64 + l],
               q3 = xw[3 * 64 + l], q4 = xw[4 * 64 + l], q5 = xw[5 * 64 + l],
               q6 = xw[6 * 64 + l], q7 = xw[7 * 64 + l];
        PROC_GROUP(10, q0, q1, q2, q3, q4, q5, q6, q7)
    }
    {
        float4 q0 = xw[8 * 64 + l], q1 = xw[9 * 64 + l], q2 = xw[10 * 64 + l],
               q3 = xw[11 * 64 + l], q4 = xw[12 * 64 + l], q5 = xw[13 * 64 + l],
               q6 = xw[14 * 64 + l], q7 = xw[15 * 64 + l];
        PROC_GROUP(11, q0, q1, q2, q3, q4, q5, q6, q7)
    }
    {
        float4 q0 = xw[16 * 64 + l], q1 = xw[17 * 64 + l], q2 = xw[18 * 64 + l],
               q3 = xw[19 * 64 + l], q4 = xw[20 * 64 + l], q5 = xw[21 * 64 + l],
               q6 = xw[22 * 64 + l], q7 = xw[23 * 64 + l];
        PROC_GROUP(12, q0, q1, q2, q3, q4, q5, q6, q7)
    }
    {
        float4 q0 = xw[24 * 64 + l], q1 = xw[25 * 64 + l], q2 = xw[26 * 64 + l],
               q3 = xw[27 * 64 + l], q4 = xw[28 * 64 + l], q5 = xw[29 * 64 + l],
               q6 = xw[30 * 64 + l], q7 = xw[31 * 64 + l];
        PROC_GROUP(13, q0, q1, q2, q3, q4, q5, q6, q7)
    }
    // re-streamed groups 14..15 (rows 112..127)
    PROC_GROUP(14, sa[0], sa[1], sa[2], sa[3], sa[4], sa[5], sa[6], sa[7])
    PROC_GROUP(15, sb[0], sb[1], sb[2], sb[3], sb[4], sb[5], sb[6], sb[7])
#undef PG_KP
#undef PROC_GROUP
#undef ACC
#undef PD

    // e store: lane l owns rows row0+l and row0+64+l (coalesced float2 x2)
    ((float2*)(ws + WS_E))[row0 + l]      = make_float2(e0c, e1c);
    ((float2*)(ws + WS_E))[row0 + 64 + l] = make_float2(e0d, e1d);
    // per-wave Z partial
    if (l == 0) {
        ws[WS_ZP + blk * 8 + w * 2 + 0] = z0;
        ws[WS_ZP + blk * 8 + w * 2 + 1] = z1;
    }
    // cross-wave U reduce in LDS (reuse pl), one coalesced 2 KB store per block
    __syncthreads();
    {
        int base = w * (D * K) + l * 8;   // col (4l+m)*2+k within wave region
        pl[base + 0] = acc0.x; pl[base + 1] = acc1.x;
        pl[base + 2] = acc0.y; pl[base + 3] = acc1.y;
        pl[base + 4] = acc0.z; pl[base + 5] = acc1.z;
        pl[base + 6] = acc0.w; pl[base + 7] = acc1.w;
    }
    __syncthreads();
    if (t < 128) {
        float4 a = ((const float4*)(pl       ))[t];
        float4 e = ((const float4*)(pl +  512))[t];
        float4 f = ((const float4*)(pl + 1024))[t];
        float4 g = ((const float4*)(pl + 1536))[t];
        float4 s4 = make_float4(a.x + e.x + f.x + g.x, a.y + e.y + f.y + g.y,
                                a.z + e.z + f.z + g.z, a.w + e.w + f.w + g.w);
        *(float4*)(ws + WS_UP + (size_t)blk * (D * K) + 4 * t) = s4;
    }

    // ---------------- phase 3: last block of each scene finalizes ----------------
    __syncthreads();
    if (t == 0) {
        __threadfence();                       // release U/Z/E partials
        int old = atomicAdd(&cntF[b], 1);
        sfin = (old == BPS - 1) ? 1 : 0;
        if (sfin) __threadfence();             // acquire peers' partials
    }
    __syncthreads();
    if (!sfin) return;

    // Z reduce: 4 blocks x 4 waves = 16 partials per channel
    if (w < 2) {
        float v = (l < 16)
                ? ws[WS_ZP + (b * BPS + (l >> 2)) * 8 + (l & 3) * 2 + w] : 0.f;
        v += __shfl_xor(v, 1); v += __shfl_xor(v, 2);
        v += __shfl_xor(v, 4); v += __shfl_xor(v, 8);
        if (l == 0) sbt[w] = v;
    }
    __syncthreads();
    float zf0 = sbt[0], zf1 = sbt[1];
    float iz0 = 1.0f / zf0, iz1 = 1.0f / zf1;

    // features: out[b*512 + j], j = d*2+k
#pragma unroll
    for (int j = t; j < D * K; j += 256) {
        float ssum = 0.f;
#pragma unroll
        for (int c = 0; c < BPS; ++c) ssum += ws[WS_UP + (b * BPS + c) * (D * K) + j];
        out[b * (D * K) + j] = ssum * ((j & 1) ? iz1 : iz0);
    }
    // weights: float4 = 2 rows at a time
    const float4* E = (const float4*)(ws + WS_E);
    float4* W = (float4*)(out + B * D * K);
#pragma unroll
    for (int i = t; i < OBJS / 2; i += 256) {
        float4 e4 = E[b * (OBJS / 2) + i];
        W[b * (OBJS / 2) + i] = make_float4(e4.x * iz0, e4.y * iz1, e4.z * iz0, e4.w * iz1);
    }
}

// ============================================================================
// Fallback path: the verified 3-kernel pipeline (used if the fused kernel
// cannot be cooperatively launched with full co-residency).
// ============================================================================
__global__ __launch_bounds__(256) void k1_partial(const float* __restrict__ x,
                                                  float* __restrict__ ws) {
    __shared__ float red[4 * D];
    int blk = blockIdx.x;
    int w = threadIdx.x >> 6, l = threadIdx.x & 63;
    int row0 = blk * CH + w * RPW;

    float4 acc = make_float4(0.f, 0.f, 0.f, 0.f);
    const float* px = x + (size_t)row0 * D + 4 * l;
#pragma unroll 8
    for (int j = 0; j < RPW; ++j) {
        float4 v = *(const float4*)(px + (size_t)j * D);
        acc.x += v.x; acc.y += v.y; acc.z += v.z; acc.w += v.w;
    }
    *(float4*)(red + w * D + 4 * l) = acc;
    __syncthreads();
    int t = threadIdx.x;
    if (t < 64) {
        float4 a = ((const float4*)(red        ))[t];
        float4 e = ((const float4*)(red +     D))[t];
        float4 f = ((const float4*)(red + 2 * D))[t];
        float4 g = ((const float4*)(red + 3 * D))[t];
        float4 s = make_float4(a.x + e.x + f.x + g.x, a.y + e.y + f.y + g.y,
                               a.z + e.z + f.z + g.z, a.w + e.w + f.w + g.w);
        *(float4*)(ws + WS_P1 + blk * D + 4 * t) = s;
    }
}

__global__ __launch_bounds__(256) void k2_main(const float* __restrict__ x,
                                               const int* __restrict__ num_objs,
                                               const float* __restrict__ att_scale,
                                               const float* __restrict__ att_shared,
                                               const float* __restrict__ channel_bias,
                                               float* __restrict__ ws) {
    __shared__ float pl[4 * 576];
    __shared__ float esm[4 * 16];
    __shared__ float sctx[D];
    __shared__ float sbt[2];

    int blk = blockIdx.x;
    int b = blk >> 4;
    int t = threadIdx.x;
    int w = t >> 6, l = t & 63;
    int r = l & 7, s = l >> 3;
    int row0 = blk * CH + w * RPW;

    {
        int cnt = num_objs[b]; if (cnt < 1) cnt = 1;
        float inv = 1.0f / (float)cnt;
        float sum = 0.f;
#pragma unroll
        for (int c = 0; c < S1; ++c) sum += ws[WS_P1 + (b * S1 + c) * D + t];
        sctx[t] = sum * inv;
    }
    if (t < 64) {
        float4 a = ((const float4*)att_shared)[t];
#pragma unroll
        for (int k = 0; k < K; ++k) {
            float4 cb = ((const float4*)(channel_bias + k * D))[t];
            float v = a.x * cb.x + a.y * cb.y + a.z * cb.z + a.w * cb.w;
#pragma unroll
            for (int m = 32; m > 0; m >>= 1) v += __shfl_xor(v, m);
            if (t == 0) sbt[k] = v;
        }
    }
    __syncthreads();

    float4 a4   = ((const float4*)att_shared)[l];
    float4 ctx4 = *(const float4*)(sctx + 4 * l);
    float bt0 = sbt[0], bt1 = sbt[1];
    float s0 = att_scale[0], s1 = att_scale[1];

    float4 acc0 = make_float4(0.f, 0.f, 0.f, 0.f);
    float4 acc1 = make_float4(0.f, 0.f, 0.f, 0.f);
    float z0 = 0.f, z1 = 0.f;
    float e0c = 0.f, e1c = 0.f;
    float* pw = pl  + w * 576;
    float* ew = esm + w * 16;
    const float* px = x + (size_t)row0 * D + 4 * l;

#pragma unroll
    for (int g = 0; g < 4; ++g) {
        float4 v0 = *(const float4*)(px + (size_t)(g * 8 + 0) * D);
        float4 v1 = *(const float4*)(px + (size_t)(g * 8 + 1) * D);
        float4 v2 = *(const float4*)(px + (size_t)(g * 8 + 2) * D);
        float4 v3 = *(const float4*)(px + (size_t)(g * 8 + 3) * D);
        float4 v4 = *(const float4*)(px + (size_t)(g * 8 + 4) * D);
        float4 v5 = *(const float4*)(px + (size_t)(g * 8 + 5) * D);
        float4 v6 = *(const float4*)(px + (size_t)(g * 8 + 6) * D);
        float4 v7 = *(const float4*)(px + (size_t)(g * 8 + 7) * D);

#define PDOT(V) (lrelu02((V).x + ctx4.x) * a4.x + lrelu02((V).y + ctx4.y) * a4.y \
               + lrelu02((V).z + ctx4.z) * a4.z + lrelu02((V).w + ctx4.w) * a4.w)
        pw[l * 9 + 0] = PDOT(v0); pw[l * 9 + 1] = PDOT(v1);
        pw[l * 9 + 2] = PDOT(v2); pw[l * 9 + 3] = PDOT(v3);
        pw[l * 9 + 4] = PDOT(v4); pw[l * 9 + 5] = PDOT(v5);
        pw[l * 9 + 6] = PDOT(v6); pw[l * 9 + 7] = PDOT(v7);
#undef PDOT
        float tr = 0.f;
#pragma unroll
        for (int q = 0; q < 8; ++q) tr += pw[(s * 8 + q) * 9 + r];
        tr += __shfl_xor(tr, 8);
        tr += __shfl_xor(tr, 16);
        tr += __shfl_xor(tr, 32);

        float e0 = __expf((tr + bt0) * s0);
        float e1 = __expf((tr + bt1) * s1);
        if (((l >> 3) & 3) == g) { e0c = e0; e1c = e1; }
        if (l < 8) { ew[2 * l] = e0; ew[2 * l + 1] = e1; }
        float4 E0 = *(const float4*)(ew + 0);
        float4 E1 = *(const float4*)(ew + 4);
        float4 E2 = *(const float4*)(ew + 8);
        float4 E3 = *(const float4*)(ew + 12);
        z0 += E0.x + E0.z + E1.x + E1.z + E2.x + E2.z + E3.x + E3.z;
        z1 += E0.y + E0.w + E1.y + E1.w + E2.y + E2.w + E3.y + E3.w;

#define ACC(V, EA, EB) { acc0.x += (V).x * (EA); acc0.y += (V).y * (EA);      \
                         acc0.z += (V).z * (EA); acc0.w += (V).w * (EA);      \
                         acc1.x += (V).x * (EB); acc1.y += (V).y * (EB);      \
                         acc1.z += (V).z * (EB); acc1.w += (V).w * (EB); }
        ACC(v0, E0.x, E0.y) ACC(v1, E0.z, E0.w)
        ACC(v2, E1.x, E1.y) ACC(v3, E1.z, E1.w)
        ACC(v4, E2.x, E2.y) ACC(v5, E2.z, E2.w)
        ACC(v6, E3.x, E3.y) ACC(v7, E3.z, E3.w)
#undef ACC
    }

    if (l < 32) ((float2*)(ws + WS_E))[row0 + l] = make_float2(e0c, e1c);
    if (l == 0) {
        ws[WS_ZP + blk * 8 + w * 2 + 0] = z0;
        ws[WS_ZP + blk * 8 + w * 2 + 1] = z1;
    }
    __syncthreads();
    {
        int base = w * (D * K) + l * 8;
        pl[base + 0] = acc0.x; pl[base + 1] = acc1.x;
        pl[base + 2] = acc0.y; pl[base + 3] = acc1.y;
        pl[base + 4] = acc0.z; pl[base + 5] = acc1.z;
        pl[base + 6] = acc0.w; pl[base + 7] = acc1.w;
    }
    __syncthreads();
    if (t < 128) {
        float4 a = ((const float4*)(pl       ))[t];
        float4 e = ((const float4*)(pl +  512))[t];
        float4 f = ((const float4*)(pl + 1024))[t];
        float4 g = ((const float4*)(pl + 1536))[t];
        float4 s4 = make_float4(a.x + e.x + f.x + g.x, a.y + e.y + f.y + g.y,
                                a.z + e.z + f.z + g.z, a.w + e.w + f.w + g.w);
        *(float4*)(ws + WS_UP + (size_t)blk * (D * K) + 4 * t) = s4;
    }
}

__global__ __launch_bounds__(256) void k3_final(const float* __restrict__ ws,
                                                float* __restrict__ out) {
    __shared__ float zsh[2];
    int b = blockIdx.x;
    int t = threadIdx.x;
    int w = t >> 6, l = t & 63;

    if (w < 2) {
        float v = ws[WS_ZP + (b * S1 + (l >> 2)) * 8 + (l & 3) * 2 + w];
#pragma unroll
        for (int m = 32; m > 0; m >>= 1) v += __shfl_xor(v, m);
        if (l == 0) zsh[w] = v;
    }
    __syncthreads();
    float z0 = zsh[0], z1 = zsh[1];
    float iz0 = 1.0f / z0, iz1 = 1.0f / z1;

#pragma unroll
    for (int j = t; j < D * K; j += 256) {
        float s = 0.f;
#pragma unroll
        for (int c = 0; c < S1; ++c) s += ws[WS_UP + (b * S1 + c) * (D * K) + j];
        out[b * (D * K) + j] = s * ((j & 1) ? iz1 : iz0);
    }
    const float4* E = (const float4*)(ws + WS_E);
    float4* W = (float4*)(out + B * D * K);
#pragma unroll
    for (int i = t; i < OBJS / 2; i += 256) {
        float4 e = E[b * (OBJS / 2) + i];
        W[b * (OBJS / 2) + i] = make_float4(e.x * iz0, e.y * iz1, e.z * iz0, e.w * iz1);
    }
}

extern "C" void kernel_launch(void* const* d_in, const int* in_sizes, int n_in,
                              void* d_out, int out_size, void* d_ws, size_t ws_size,
                              hipStream_t stream) {
    const float* x            = (const float*)d_in[0];   // [N, D]
    const int*   num_objs     = (const int*)d_in[1];     // [B]
    const float* att_shared   = (const float*)d_in[2];   // [1, D]
    const float* att_scale    = (const float*)d_in[3];   // [K, 1]
    const float* channel_bias = (const float*)d_in[4];   // [K, D]
    float* ws  = (float*)d_ws;
    float* out = (float*)d_out;

    const int DYN_LDS = 4 * 32 * 64 * (int)sizeof(float4);   // 128 KB xbuf

    // One-time check: can the fused kernel keep all 256 blocks co-resident?
    static int coop_ok = -1;
    if (coop_ok < 0) {
        (void)hipFuncSetAttribute((const void*)fused_all,
                                  hipFuncAttributeMaxDynamicSharedMemorySize,
                                  DYN_LDS);
        int nb = 0;
        hipError_t e = hipOccupancyMaxActiveBlocksPerMultiprocessor(
                &nb, fused_all, 256, DYN_LDS);
        coop_ok = (e == hipSuccess && nb >= 1) ? 1 : 0;
    }

    if (coop_ok) {
        // ws is re-poisoned each iteration: counters MUST be zeroed in-graph.
        hipMemsetAsync((char*)d_ws + sizeof(float) * (size_t)WS_CNT, 0,
                       2 * B * sizeof(int), stream);
        void* args[] = {(void*)&x, (void*)&num_objs, (void*)&att_scale,
                        (void*)&att_shared, (void*)&channel_bias,
                        (void*)&ws, (void*)&out};
        hipError_t e = hipLaunchCooperativeKernel((void*)fused_all,
                                                  dim3(NBLK), dim3(256),
                                                  args, DYN_LDS, stream);
        if (e == hipSuccess) return;
        coop_ok = 0;  // fall through to the proven 3-kernel path
    }

    k1_partial<<<B * S1, 256, 0, stream>>>(x, ws);
    k2_main<<<B * S1, 256, 0, stream>>>(x, num_objs, att_scale, att_shared,
                                        channel_bias, ws);
    k3_final<<<B, 256, 0, stream>>>(ws, out);
}